// Round 1
// baseline (353.754 us; speedup 1.0000x reference)
//
#include <hip/hip_runtime.h>
#include <cfloat>

constexpr int BB   = 8;
constexpr int NGT_ = 10000;
constexpr int NP0 = 156,  NP1 = 618,  NP2 = 2466;
constexpr int NE0 = 462,  NE1 = 1848, NE2 = 7392;

// ---------- monotone float<->uint map for atomicMin on floats ----------
__device__ inline unsigned fkey(float f){
  unsigned u = __float_as_uint(f);
  return (u & 0x80000000u) ? ~u : (u | 0x80000000u);
}
__device__ inline float fdec(unsigned k){
  unsigned u = (k & 0x80000000u) ? (k ^ 0x80000000u) : ~k;
  return __uint_as_float(u);
}

// =====================================================================
// Chamfer direction 1: for each gt point, min over rest points.
// Block: 256 threads, one gt point per thread; rest tile in LDS.
// =====================================================================
__global__ void __launch_bounds__(256) chamfer_d1_k(
    const float* __restrict__ gt, const float* __restrict__ rest,
    int n, float scale, float* __restrict__ out)
{
  extern __shared__ float4 sr[];
  __shared__ float red[4];
  const int b = blockIdx.y;
  const float* rb = rest + (size_t)b * n * 3;
  for (int m = threadIdx.x; m < n; m += 256) {
    float x = rb[m*3], y = rb[m*3+1], z = rb[m*3+2];
    sr[m] = make_float4(x, y, z, x*x + y*y + z*z);
  }
  __syncthreads();

  const int gi = blockIdx.x * 256 + threadIdx.x;
  float vmin = 0.f;
  if (gi < NGT_) {
    const float* a = gt + ((size_t)b * NGT_ + gi) * 3;
    float ax = a[0], ay = a[1], az = a[2];
    float sa = ax*ax + ay*ay + az*az;
    float v = FLT_MAX;
    #pragma unroll 4
    for (int m = 0; m < n; ++m) {
      float4 r = sr[m];
      float dot = ax*r.x + ay*r.y + az*r.z;
      float d = fmaf(-2.f, dot, sa + r.w);
      v = fminf(v, d);
    }
    vmin = v;
  }
  // block sum
  #pragma unroll
  for (int o = 32; o; o >>= 1) vmin += __shfl_xor(vmin, o);
  if ((threadIdx.x & 63) == 0) red[threadIdx.x >> 6] = vmin;
  __syncthreads();
  if (threadIdx.x == 0)
    atomicAdd(out + 3, (red[0] + red[1] + red[2] + red[3]) * scale);
}

// =====================================================================
// Chamfer direction 2: for each rest point, min over gt points.
// Wave handles 8 rest points x one 2048-wide gt chunk; atomicMin to ws.
// =====================================================================
constexpr int R_  = 8;
constexpr int GCH = 2048;
constexpr int NCH = (NGT_ + GCH - 1) / GCH;           // 5
constexpr int G0 = (NP0 + R_-1)/R_;                   // 20
constexpr int G1 = (NP1 + R_-1)/R_;                   // 78
constexpr int G2 = (NP2 + R_-1)/R_;                   // 309
constexpr int I0 = BB*G0*NCH, I1 = BB*G1*NCH, I2 = BB*G2*NCH;  // 800,3120,12360
constexpr int TOT_ITEMS = I0 + I1 + I2;               // 16280
constexpr int WS_TOT = BB * (NP0 + NP1 + NP2);        // 25920

template<int NPt>
__device__ void d2_work(const float* __restrict__ gt, const float* __restrict__ rest,
                        unsigned* __restrict__ ws, int rem, int lane)
{
  constexpr int Gr = (NPt + R_-1)/R_;
  int chunk = rem % NCH; rem /= NCH;
  int grp = rem % Gr;
  int b   = rem / Gr;
  int m0  = grp * R_;

  float bx[R_], by[R_], bz[R_], sb[R_], vmin[R_];
  #pragma unroll
  for (int r = 0; r < R_; ++r) {
    int m = m0 + r; if (m > NPt - 1) m = NPt - 1;
    const float* p = rest + ((size_t)b * NPt + m) * 3;
    float x = p[0], y = p[1], z = p[2];
    bx[r] = x; by[r] = y; bz[r] = z; sb[r] = x*x + y*y + z*z;
    vmin[r] = FLT_MAX;
  }

  int k0 = chunk * GCH;
  int k1 = k0 + GCH; if (k1 > NGT_) k1 = NGT_;
  const float* gb = gt + (size_t)b * NGT_ * 3;
  for (int k = k0 + lane; k < k1; k += 64) {
    float gx = gb[k*3], gy = gb[k*3+1], gz = gb[k*3+2];
    float sg = gx*gx + gy*gy + gz*gz;
    #pragma unroll
    for (int r = 0; r < R_; ++r) {
      float dot = gx*bx[r] + gy*by[r] + gz*bz[r];
      float d = fmaf(-2.f, dot, sg + sb[r]);
      vmin[r] = fminf(vmin[r], d);
    }
  }
  #pragma unroll
  for (int r = 0; r < R_; ++r) {
    float v = vmin[r];
    #pragma unroll
    for (int o = 32; o; o >>= 1) v = fminf(v, __shfl_xor(v, o));
    if (lane == 0 && (m0 + r) < NPt)
      atomicMin(&ws[(size_t)b * NPt + m0 + r], fkey(v));
  }
}

__global__ void __launch_bounds__(256) chamfer_d2_k(
    const float* __restrict__ gt,
    const float* __restrict__ r0, const float* __restrict__ r1, const float* __restrict__ r2,
    unsigned* __restrict__ ws)
{
  int wid = __builtin_amdgcn_readfirstlane((int)((blockIdx.x * blockDim.x + threadIdx.x) >> 6));
  int lane = threadIdx.x & 63;
  if (wid < I0)            d2_work<NP0>(gt, r0, ws,                  wid,          lane);
  else if (wid < I0 + I1)  d2_work<NP1>(gt, r1, ws + BB*NP0,         wid - I0,     lane);
  else if (wid < TOT_ITEMS)d2_work<NP2>(gt, r2, ws + BB*(NP0+NP1),   wid - I0 - I1, lane);
}

__global__ void __launch_bounds__(256) d2_finish_k(
    const unsigned* __restrict__ ws, float* __restrict__ out)
{
  __shared__ float red[4];
  int t = blockIdx.x * 256 + threadIdx.x;
  float v = 0.f;
  if (t < WS_TOT) {
    float d = fdec(ws[t]);
    float sc;
    if (t < BB*NP0)              sc = 0.55f / (BB * NP0);
    else if (t < BB*(NP0+NP1))   sc = 0.55f / (BB * NP1);
    else                         sc = 0.55f / (BB * NP2);
    v = d * sc;
  }
  #pragma unroll
  for (int o = 32; o; o >>= 1) v += __shfl_xor(v, o);
  if ((threadIdx.x & 63) == 0) red[threadIdx.x >> 6] = v;
  __syncthreads();
  if (threadIdx.x == 0)
    atomicAdd(out + 3, red[0] + red[1] + red[2] + red[3]);
}

// =====================================================================
// Edge loss
// =====================================================================
__global__ void __launch_bounds__(256) edge_k(
    const float* __restrict__ pred, const int* __restrict__ edges,
    int n, int ne, float scale, float* __restrict__ out)
{
  __shared__ float red[4];
  const int b = blockIdx.y;
  const int e = blockIdx.x * 256 + threadIdx.x;
  float s = 0.f;
  if (e < ne) {
    int e0 = edges[2*e], e1 = edges[2*e+1];
    const float* p0 = pred + ((size_t)b * n + e0) * 3;
    const float* p1 = pred + ((size_t)b * n + e1) * 3;
    float dx = p0[0]-p1[0], dy = p0[1]-p1[1], dz = p0[2]-p1[2];
    s = dx*dx + dy*dy + dz*dz;
  }
  #pragma unroll
  for (int o = 32; o; o >>= 1) s += __shfl_xor(s, o);
  if ((threadIdx.x & 63) == 0) red[threadIdx.x >> 6] = s;
  __syncthreads();
  if (threadIdx.x == 0)
    atomicAdd(out + 0, (red[0] + red[1] + red[2] + red[3]) * scale);
}

// =====================================================================
// Laplace + move loss  (l1 - l2 == laplace(before - pred))
// =====================================================================
__global__ void __launch_bounds__(256) lap_k(
    const float* __restrict__ before, const float* __restrict__ pred,
    const int* __restrict__ lap, int n, float lscale, float mscale,
    float* __restrict__ out)
{
  __shared__ float red[4], red2[4];
  const int b = blockIdx.y;
  const int v = blockIdx.x * 256 + threadIdx.x;
  float ls = 0.f, ms = 0.f;
  if (v < n) {
    const float* bb = before + (size_t)b * n * 3;
    const float* pp = pred   + (size_t)b * n * 3;
    float dx = bb[v*3]   - pp[v*3];
    float dy = bb[v*3+1] - pp[v*3+1];
    float dz = bb[v*3+2] - pp[v*3+2];
    float ax = 0.f, ay = 0.f, az = 0.f;
    #pragma unroll
    for (int j = 0; j < 8; ++j) {
      int id = lap[v*10 + j];
      if (id >= 0) {
        ax += bb[id*3]   - pp[id*3];
        ay += bb[id*3+1] - pp[id*3+1];
        az += bb[id*3+2] - pp[id*3+2];
      }
    }
    float cnt = (float)lap[v*10 + 9];
    float lx = dx - ax / cnt;
    float ly = dy - ay / cnt;
    float lz = dz - az / cnt;
    ls = lx*lx + ly*ly + lz*lz;
    ms = dx*dx + dy*dy + dz*dz;
  }
  #pragma unroll
  for (int o = 32; o; o >>= 1) { ls += __shfl_xor(ls, o); ms += __shfl_xor(ms, o); }
  if ((threadIdx.x & 63) == 0) { red[threadIdx.x>>6] = ls; red2[threadIdx.x>>6] = ms; }
  __syncthreads();
  if (threadIdx.x == 0) {
    atomicAdd(out + 1, (red[0]+red[1]+red[2]+red[3]) * lscale);
    if (mscale != 0.f)
      atomicAdd(out + 2, (red2[0]+red2[1]+red2[2]+red2[3]) * mscale);
  }
}

// =====================================================================
extern "C" void kernel_launch(void* const* d_in, const int* in_sizes, int n_in,
                              void* d_out, int out_size, void* d_ws, size_t ws_size,
                              hipStream_t stream)
{
  // setup_inputs() dict order:
  // 0: gt_coord; then per level i: pred_coord_i, pred_before_i, rest_coord_i, lap_idx_i, edges_i
  const float* gt        = (const float*)d_in[0];
  const float* pred[3]   = {(const float*)d_in[1],  (const float*)d_in[6],  (const float*)d_in[11]};
  const float* before[3] = {(const float*)d_in[2],  (const float*)d_in[7],  (const float*)d_in[12]};
  const float* rest[3]   = {(const float*)d_in[3],  (const float*)d_in[8],  (const float*)d_in[13]};
  const int*   lap[3]    = {(const int*)d_in[4],    (const int*)d_in[9],    (const int*)d_in[14]};
  const int*   edges[3]  = {(const int*)d_in[5],    (const int*)d_in[10],   (const int*)d_in[15]};
  float* out = (float*)d_out;
  unsigned* ws = (unsigned*)d_ws;

  const int   NP[3]   = {NP0, NP1, NP2};
  const int   NE[3]   = {NE0, NE1, NE2};
  const float LAPC[3] = {0.2f, 1.0f, 1.0f};

  hipMemsetAsync(out, 0, 4 * sizeof(float), stream);
  hipMemsetAsync(ws, 0xFF, WS_TOT * sizeof(unsigned), stream);

  // chamfer d1: per gt point
  for (int i = 0; i < 3; ++i) {
    dim3 g((NGT_ + 255) / 256, BB);
    chamfer_d1_k<<<g, 256, NP[i] * 16, stream>>>(gt, rest[i], NP[i],
                                                 1.f / (BB * NGT_), out);
  }
  // chamfer d2: per rest point (all levels in one launch)
  {
    int blocks = (TOT_ITEMS * 64 + 255) / 256;   // 4070
    chamfer_d2_k<<<blocks, 256, 0, stream>>>(gt, rest[0], rest[1], rest[2], ws);
    d2_finish_k<<<(WS_TOT + 255) / 256, 256, 0, stream>>>(ws, out);
  }
  // edge loss
  for (int i = 0; i < 3; ++i) {
    dim3 g((NE[i] + 255) / 256, BB);
    edge_k<<<g, 256, 0, stream>>>(pred[i], edges[i], NP[i], NE[i],
                                  1.f / (BB * NE[i]), out);
  }
  // laplace + move loss
  for (int i = 0; i < 3; ++i) {
    dim3 g((NP[i] + 255) / 256, BB);
    lap_k<<<g, 256, 0, stream>>>(before[i], pred[i], lap[i], NP[i],
                                 LAPC[i] / (BB * NP[i]),
                                 i > 0 ? LAPC[i] / (BB * NP[i]) : 0.f,
                                 out);
  }
}